// Round 5
// baseline (635.919 us; speedup 1.0000x reference)
//
#include <hip/hip_runtime.h>
#include <hip/hip_bf16.h>
#include <cmath>

#define D 256
#define NH 8
#define B 2
#define EPW 4   // edges per wave

// ---- ordered-uint mapping for float atomicMax ----
__device__ inline unsigned f2ord(float f) {
    unsigned u = __float_as_uint(f);
    return (u & 0x80000000u) ? ~u : (u | 0x80000000u);
}
__device__ inline float ord2f(unsigned u) {
    unsigned b = (u & 0x80000000u) ? (u & 0x7FFFFFFFu) : ~u;
    return __uint_as_float(b);
}
__device__ inline unsigned short f2bf(float f) {
    unsigned u = __float_as_uint(f);
    unsigned r = u + 0x7FFFu + ((u >> 16) & 1u);   // round-to-nearest-even
    return (unsigned short)(r >> 16);
}

// K0: fp32 [bb][node][d] -> packed bf16 [node][bb][d] (1KB per node covers
// both batches). One thread = 4 d-values of q AND k.
__global__ __launch_bounds__(256) void k_conv(
    const float* __restrict__ q, const float* __restrict__ k,
    ushort4* __restrict__ qc, ushort4* __restrict__ kc, int n)
{
    int total = n * B * (D / 4);
    for (int i = blockIdx.x * blockDim.x + threadIdx.x; i < total;
         i += gridDim.x * blockDim.x) {
        int d4  = i & 63;
        int row = i >> 6;                 // bb*n + node (source row order)
        int bb  = (row >= n) ? 1 : 0;
        int node = row - bb * n;
        const float4 a = ((const float4*)q)[(size_t)row * 64 + d4];
        const float4 b = ((const float4*)k)[(size_t)row * 64 + d4];
        size_t dst = ((size_t)node * B + bb) * 64 + d4;
        qc[dst] = make_ushort4(f2bf(a.x), f2bf(a.y), f2bf(a.z), f2bf(a.w));
        kc[dst] = make_ushort4(f2bf(b.x), f2bf(b.y), f2bf(b.z), f2bf(b.w));
    }
}

// K1: bf16 gather + scores + fused block-max. One wave = EPW edges; one uint4
// load per array covers both batches (lanes 0-31 bb=0, 32-63 bb=1; 4
// lanes/head). Raw scores to s[b][m][8]; block max -> one atomicMax.
__global__ __launch_bounds__(256) void k_scores_bf(
    const ushort* __restrict__ qc, const ushort* __restrict__ kc,
    const int* __restrict__ e, float* __restrict__ s,
    unsigned* __restrict__ gmax, int m)
{
    int wave = (int)((blockIdx.x * blockDim.x + threadIdx.x) >> 6);
    int lane = threadIdx.x & 63;
    int j0 = wave * EPW;

    int e0[EPW], e1[EPW];
    #pragma unroll
    for (int t = 0; t < EPW; ++t) {
        int j = j0 + t;
        int ok = (j < m);
        e0[t] = ok ? e[j]     : 0;
        e1[t] = ok ? e[m + j] : 0;
    }

    uint4 qa[EPW], kb[EPW];
    #pragma unroll
    for (int t = 0; t < EPW; ++t) {
        qa[t] = ((const uint4*)(qc + (size_t)e0[t] * (B * D)))[lane];
        kb[t] = ((const uint4*)(kc + (size_t)e1[t] * (B * D)))[lane];
    }

    float wmax = -INFINITY;
    #pragma unroll
    for (int t = 0; t < EPW; ++t) {
        float p = 0.f;
        const unsigned* qw = (const unsigned*)&qa[t];
        const unsigned* kw = (const unsigned*)&kb[t];
        #pragma unroll
        for (int w = 0; w < 4; ++w) {
            float ql = __uint_as_float(qw[w] << 16);
            float qh = __uint_as_float(qw[w] & 0xFFFF0000u);
            float kl = __uint_as_float(kw[w] << 16);
            float kh = __uint_as_float(kw[w] & 0xFFFF0000u);
            p = fmaf(ql, kl, p);
            p = fmaf(qh, kh, p);
        }
        p += __shfl_xor(p, 1);
        p += __shfl_xor(p, 2);
        float sc = p * 0.0625f;           // /sqrt(256)
        bool valid = (j0 + t) < m;
        if (valid) wmax = fmaxf(wmax, sc);
        if ((lane & 3) == 0 && valid) {
            int bb = lane >> 5;
            int h  = (lane >> 2) & 7;
            s[((size_t)bb * m + (j0 + t)) * NH + h] = sc;
        }
    }

    // full-wave max (scores replicated across 4-lane groups; reduce all offs)
    #pragma unroll
    for (int off = 1; off <= 32; off <<= 1)
        wmax = fmaxf(wmax, __shfl_xor(wmax, off));
    __shared__ float sm[4];
    if (lane == 0) sm[threadIdx.x >> 6] = wmax;
    __syncthreads();
    if (threadIdx.x == 0) {
        float bm = fmaxf(fmaxf(sm[0], sm[1]), fmaxf(sm[2], sm[3]));
        if (bm > -INFINITY) atomicMax(gmax, f2ord(bm));
    }
}

// K2: one thread per (bb, edge). float4 exp in-place; 8 atomicAdds into seg.
__global__ __launch_bounds__(256) void k_exp_seg(
    float* __restrict__ s, const int* __restrict__ r,
    const unsigned* __restrict__ gmax, float* __restrict__ seg, int m)
{
    int i = blockIdx.x * blockDim.x + threadIdx.x;
    int total = B * m;
    if (i >= total) return;
    float M = ord2f(*gmax);
    int bb = (i >= m) ? 1 : 0;
    int j  = i - bb * m;
    float4* sp = (float4*)(s + (size_t)i * NH);
    float4 x0 = sp[0], x1 = sp[1];
    x0.x = expf(x0.x - M); x0.y = expf(x0.y - M);
    x0.z = expf(x0.z - M); x0.w = expf(x0.w - M);
    x1.x = expf(x1.x - M); x1.y = expf(x1.y - M);
    x1.z = expf(x1.z - M); x1.w = expf(x1.w - M);
    sp[0] = x0; sp[1] = x1;
    float* sg = seg + ((size_t)r[j] * B + bb) * NH;
    atomicAdd(&sg[0], x0.x); atomicAdd(&sg[1], x0.y);
    atomicAdd(&sg[2], x0.z); atomicAdd(&sg[3], x0.w);
    atomicAdd(&sg[4], x1.x); atomicAdd(&sg[5], x1.y);
    atomicAdd(&sg[6], x1.z); atomicAdd(&sg[7], x1.w);
}

// K3: one thread per (bb, edge). out = ex / (seg + eps), float4 in-place.
__global__ __launch_bounds__(256) void k_norm(
    float* __restrict__ s, const int* __restrict__ r,
    const float* __restrict__ seg, int m)
{
    int i = blockIdx.x * blockDim.x + threadIdx.x;
    int total = B * m;
    if (i >= total) return;
    int bb = (i >= m) ? 1 : 0;
    int j  = i - bb * m;
    const float4* sg = (const float4*)(seg + ((size_t)r[j] * B + bb) * NH);
    float4* sp = (float4*)(s + (size_t)i * NH);
    float4 d0 = sg[0], d1 = sg[1];
    float4 x0 = sp[0], x1 = sp[1];
    x0.x /= (d0.x + 1e-16f); x0.y /= (d0.y + 1e-16f);
    x0.z /= (d0.z + 1e-16f); x0.w /= (d0.w + 1e-16f);
    x1.x /= (d1.x + 1e-16f); x1.y /= (d1.y + 1e-16f);
    x1.z /= (d1.z + 1e-16f); x1.w /= (d1.w + 1e-16f);
    sp[0] = x0; sp[1] = x1;
}

extern "C" void kernel_launch(void* const* d_in, const int* in_sizes, int n_in,
                              void* d_out, int out_size, void* d_ws, size_t ws_size,
                              hipStream_t stream) {
    const float* q = (const float*)d_in[0];
    const float* k = (const float*)d_in[1];
    const int*   e = (const int*)d_in[2];
    const int*   r = (const int*)d_in[3];
    float* s = (float*)d_out;

    int n = in_sizes[0] / (B * D);          // 20000
    int m = in_sizes[3];                    // 320000

    // ws layout: gmax @0 (16B) | seg @16 | qc | kc
    size_t seg_bytes = (size_t)n * B * NH * sizeof(float);         // 1.28 MB
    size_t row_bytes = (size_t)n * B * D * sizeof(unsigned short); // 20.48 MB
    unsigned* gmax = (unsigned*)d_ws;
    float*    seg  = (float*)((char*)d_ws + 16);
    ushort*   qc   = (ushort*)((char*)d_ws + 16 + seg_bytes);
    ushort*   kc   = (ushort*)((char*)d_ws + 16 + seg_bytes + row_bytes);

    hipMemsetAsync(d_ws, 0, 16 + seg_bytes, stream);

    int waves  = (m + EPW - 1) / EPW;
    int sblocks = (waves + 3) / 4;
    int eblocks = (B * m + 255) / 256;

    k_conv<<<4096, 256, 0, stream>>>(q, k, (ushort4*)qc, (ushort4*)kc, n);
    k_scores_bf<<<sblocks, 256, 0, stream>>>(qc, kc, e, s, gmax, m);
    k_exp_seg<<<eblocks, 256, 0, stream>>>(s, r, gmax, seg, m);
    k_norm<<<eblocks, 256, 0, stream>>>(s, r, seg, m);
}

// Round 6
// 430.035 us; speedup vs baseline: 1.4788x; 1.4788x over previous
//
#include <hip/hip_runtime.h>
#include <hip/hip_bf16.h>
#include <cmath>

#define D 256
#define NH 8
#define B 2
#define EPW 4   // edges per wave

// ---- ordered-uint mapping for float atomicMax ----
__device__ inline unsigned f2ord(float f) {
    unsigned u = __float_as_uint(f);
    return (u & 0x80000000u) ? ~u : (u | 0x80000000u);
}
__device__ inline float ord2f(unsigned u) {
    unsigned b = (u & 0x80000000u) ? (u & 0x7FFFFFFFu) : ~u;
    return __uint_as_float(b);
}
__device__ inline unsigned short f2bf(float f) {
    unsigned u = __float_as_uint(f);
    unsigned r = u + 0x7FFFu + ((u >> 16) & 1u);   // round-to-nearest-even
    return (unsigned short)(r >> 16);
}

// K0: fp32 [bb][node][d] -> packed bf16 [node][bb][d] (1KB per node covers
// both batches). One thread = 4 d-values of q AND k.
__global__ __launch_bounds__(256) void k_conv(
    const float* __restrict__ q, const float* __restrict__ k,
    ushort4* __restrict__ qc, ushort4* __restrict__ kc, int n)
{
    int total = n * B * (D / 4);
    for (int i = blockIdx.x * blockDim.x + threadIdx.x; i < total;
         i += gridDim.x * blockDim.x) {
        int d4  = i & 63;
        int row = i >> 6;                 // bb*n + node (source row order)
        int bb  = (row >= n) ? 1 : 0;
        int node = row - bb * n;
        const float4 a = ((const float4*)q)[(size_t)row * 64 + d4];
        const float4 b = ((const float4*)k)[(size_t)row * 64 + d4];
        size_t dst = ((size_t)node * B + bb) * 64 + d4;
        qc[dst] = make_ushort4(f2bf(a.x), f2bf(a.y), f2bf(a.z), f2bf(a.w));
        kc[dst] = make_ushort4(f2bf(b.x), f2bf(b.y), f2bf(b.z), f2bf(b.w));
    }
}

// K1: bf16 gather + scores + fused block-max. One wave = EPW edges; one uint4
// load per array covers both batches (lanes 0-31 bb=0, 32-63 bb=1; 4
// lanes/head). Raw scores to s[b][m][8]; block max -> one atomicMax.
__global__ __launch_bounds__(256) void k_scores_bf(
    const ushort* __restrict__ qc, const ushort* __restrict__ kc,
    const int* __restrict__ e, float* __restrict__ s,
    unsigned* __restrict__ gmax, int m)
{
    int wave = (int)((blockIdx.x * blockDim.x + threadIdx.x) >> 6);
    int lane = threadIdx.x & 63;
    int j0 = wave * EPW;

    int e0[EPW], e1[EPW];
    #pragma unroll
    for (int t = 0; t < EPW; ++t) {
        int j = j0 + t;
        int ok = (j < m);
        e0[t] = ok ? e[j]     : 0;
        e1[t] = ok ? e[m + j] : 0;
    }

    uint4 qa[EPW], kb[EPW];
    #pragma unroll
    for (int t = 0; t < EPW; ++t) {
        qa[t] = ((const uint4*)(qc + (size_t)e0[t] * (B * D)))[lane];
        kb[t] = ((const uint4*)(kc + (size_t)e1[t] * (B * D)))[lane];
    }

    float wmax = -INFINITY;
    #pragma unroll
    for (int t = 0; t < EPW; ++t) {
        float p = 0.f;
        const unsigned* qw = (const unsigned*)&qa[t];
        const unsigned* kw = (const unsigned*)&kb[t];
        #pragma unroll
        for (int w = 0; w < 4; ++w) {
            float ql = __uint_as_float(qw[w] << 16);
            float qh = __uint_as_float(qw[w] & 0xFFFF0000u);
            float kl = __uint_as_float(kw[w] << 16);
            float kh = __uint_as_float(kw[w] & 0xFFFF0000u);
            p = fmaf(ql, kl, p);
            p = fmaf(qh, kh, p);
        }
        p += __shfl_xor(p, 1);
        p += __shfl_xor(p, 2);
        float sc = p * 0.0625f;           // /sqrt(256)
        bool valid = (j0 + t) < m;
        if (valid) wmax = fmaxf(wmax, sc);
        if ((lane & 3) == 0 && valid) {
            int bb = lane >> 5;
            int h  = (lane >> 2) & 7;
            s[((size_t)bb * m + (j0 + t)) * NH + h] = sc;
        }
    }

    // full-wave max, then block max -> one atomicMax
    #pragma unroll
    for (int off = 1; off <= 32; off <<= 1)
        wmax = fmaxf(wmax, __shfl_xor(wmax, off));
    __shared__ float sm[4];
    if (lane == 0) sm[threadIdx.x >> 6] = wmax;
    __syncthreads();
    if (threadIdx.x == 0) {
        float bm = fmaxf(fmaxf(sm[0], sm[1]), fmaxf(sm[2], sm[3]));
        if (bm > -INFINITY) atomicMax(gmax, f2ord(bm));
    }
}

// K2: ex = exp(s - M) in-place; atomicAdd into seg. ELEMENT-per-thread:
// consecutive lanes = consecutive heads of the same edge -> a wave's atomic
// instruction touches ~8 clustered seg rows, not 64 random lines. (R4 form —
// the R5 edge-per-thread variant was 3x slower: 64-way address divergence.)
__global__ __launch_bounds__(256) void k_exp_seg(
    float* __restrict__ s, const int* __restrict__ r,
    const unsigned* __restrict__ gmax, float* __restrict__ seg, int m)
{
    float M = ord2f(*gmax);
    size_t total = (size_t)B * m * NH;
    for (size_t i = blockIdx.x * (size_t)blockDim.x + threadIdx.x; i < total;
         i += (size_t)gridDim.x * blockDim.x) {
        float ex = expf(s[i] - M);
        s[i] = ex;
        size_t bj = i >> 3;               // bb*m + j
        int h  = (int)(i & 7);
        int bb = (bj >= (size_t)m) ? 1 : 0;
        int j  = (int)(bj - (size_t)bb * m);
        atomicAdd(&seg[((size_t)r[j] * B + bb) * NH + h], ex);
    }
}

// K3: one thread per (bb, edge). out = ex / (seg + eps), float4 in-place.
__global__ __launch_bounds__(256) void k_norm(
    float* __restrict__ s, const int* __restrict__ r,
    const float* __restrict__ seg, int m)
{
    int i = blockIdx.x * blockDim.x + threadIdx.x;
    int total = B * m;
    if (i >= total) return;
    int bb = (i >= m) ? 1 : 0;
    int j  = i - bb * m;
    const float4* sg = (const float4*)(seg + ((size_t)r[j] * B + bb) * NH);
    float4* sp = (float4*)(s + (size_t)i * NH);
    float4 d0 = sg[0], d1 = sg[1];
    float4 x0 = sp[0], x1 = sp[1];
    x0.x /= (d0.x + 1e-16f); x0.y /= (d0.y + 1e-16f);
    x0.z /= (d0.z + 1e-16f); x0.w /= (d0.w + 1e-16f);
    x1.x /= (d1.x + 1e-16f); x1.y /= (d1.y + 1e-16f);
    x1.z /= (d1.z + 1e-16f); x1.w /= (d1.w + 1e-16f);
    sp[0] = x0; sp[1] = x1;
}

extern "C" void kernel_launch(void* const* d_in, const int* in_sizes, int n_in,
                              void* d_out, int out_size, void* d_ws, size_t ws_size,
                              hipStream_t stream) {
    const float* q = (const float*)d_in[0];
    const float* k = (const float*)d_in[1];
    const int*   e = (const int*)d_in[2];
    const int*   r = (const int*)d_in[3];
    float* s = (float*)d_out;

    int n = in_sizes[0] / (B * D);          // 20000
    int m = in_sizes[3];                    // 320000

    // ws layout: gmax @0 (16B) | seg @16 | qc | kc
    size_t seg_bytes = (size_t)n * B * NH * sizeof(float);         // 1.28 MB
    size_t row_bytes = (size_t)n * B * D * sizeof(unsigned short); // 20.48 MB
    unsigned* gmax = (unsigned*)d_ws;
    float*    seg  = (float*)((char*)d_ws + 16);
    ushort*   qc   = (ushort*)((char*)d_ws + 16 + seg_bytes);
    ushort*   kc   = (ushort*)((char*)d_ws + 16 + seg_bytes + row_bytes);

    hipMemsetAsync(d_ws, 0, 16 + seg_bytes, stream);

    int waves   = (m + EPW - 1) / EPW;
    int sblocks = (waves + 3) / 4;
    int nblocks = (B * m + 255) / 256;

    k_conv<<<4096, 256, 0, stream>>>(q, k, (ushort4*)qc, (ushort4*)kc, n);
    k_scores_bf<<<sblocks, 256, 0, stream>>>(qc, kc, e, s, gmax, m);
    k_exp_seg<<<4096, 256, 0, stream>>>(s, r, gmax, seg, m);
    k_norm<<<nblocks, 256, 0, stream>>>(s, r, seg, m);
}

// Round 7
// 281.988 us; speedup vs baseline: 2.2551x; 1.5250x over previous
//
#include <hip/hip_runtime.h>
#include <hip/hip_bf16.h>
#include <cmath>

#define D 256
#define NH 8
#define B 2
#define EPW 4   // edges per wave

// ---- ordered-uint mapping for float atomicMax ----
__device__ inline unsigned f2ord(float f) {
    unsigned u = __float_as_uint(f);
    return (u & 0x80000000u) ? ~u : (u | 0x80000000u);
}
__device__ inline float ord2f(unsigned u) {
    unsigned b = (u & 0x80000000u) ? (u & 0x7FFFFFFFu) : ~u;
    return __uint_as_float(b);
}
__device__ inline unsigned short f2bf(float f) {
    unsigned u = __float_as_uint(f);
    unsigned r = u + 0x7FFFu + ((u >> 16) & 1u);   // round-to-nearest-even
    return (unsigned short)(r >> 16);
}

// K0: fp32 [bb][node][d] -> packed bf16 [node][bb][d] (1KB per node covers
// both batches). One thread = 4 d-values of q AND k.
__global__ __launch_bounds__(256) void k_conv(
    const float* __restrict__ q, const float* __restrict__ k,
    ushort4* __restrict__ qc, ushort4* __restrict__ kc, int n)
{
    int total = n * B * (D / 4);
    for (int i = blockIdx.x * blockDim.x + threadIdx.x; i < total;
         i += gridDim.x * blockDim.x) {
        int d4  = i & 63;
        int row = i >> 6;                 // bb*n + node (source row order)
        int bb  = (row >= n) ? 1 : 0;
        int node = row - bb * n;
        const float4 a = ((const float4*)q)[(size_t)row * 64 + d4];
        const float4 b = ((const float4*)k)[(size_t)row * 64 + d4];
        size_t dst = ((size_t)node * B + bb) * 64 + d4;
        qc[dst] = make_ushort4(f2bf(a.x), f2bf(a.y), f2bf(a.z), f2bf(a.w));
        kc[dst] = make_ushort4(f2bf(b.x), f2bf(b.y), f2bf(b.z), f2bf(b.w));
    }
}

// K1: bf16 gather + scores. One wave = EPW edges; one uint4 load per array
// covers both batches (lanes 0-31 bb=0, 32-63 bb=1; 4 lanes/head). Raw scores
// to s[b][m][8]. Wave-max -> plain store to partials[wave] (NO atomics, NO
// barrier: 20k same-address atomicMax cost ~150us in R5/R6 — serialized at
// the device coherence point).
__global__ __launch_bounds__(256) void k_scores_bf(
    const ushort* __restrict__ qc, const ushort* __restrict__ kc,
    const int* __restrict__ e, float* __restrict__ s,
    float* __restrict__ partials, int m)
{
    int wave = (int)((blockIdx.x * blockDim.x + threadIdx.x) >> 6);
    int lane = threadIdx.x & 63;
    int j0 = wave * EPW;
    if (j0 >= m) return;

    int e0[EPW], e1[EPW];
    #pragma unroll
    for (int t = 0; t < EPW; ++t) {
        int j = j0 + t;
        int ok = (j < m);
        e0[t] = ok ? e[j]     : 0;
        e1[t] = ok ? e[m + j] : 0;
    }

    uint4 qa[EPW], kb[EPW];
    #pragma unroll
    for (int t = 0; t < EPW; ++t) {
        qa[t] = ((const uint4*)(qc + (size_t)e0[t] * (B * D)))[lane];
        kb[t] = ((const uint4*)(kc + (size_t)e1[t] * (B * D)))[lane];
    }

    float wmax = -INFINITY;
    #pragma unroll
    for (int t = 0; t < EPW; ++t) {
        float p = 0.f;
        const unsigned* qw = (const unsigned*)&qa[t];
        const unsigned* kw = (const unsigned*)&kb[t];
        #pragma unroll
        for (int w = 0; w < 4; ++w) {
            float ql = __uint_as_float(qw[w] << 16);
            float qh = __uint_as_float(qw[w] & 0xFFFF0000u);
            float kl = __uint_as_float(kw[w] << 16);
            float kh = __uint_as_float(kw[w] & 0xFFFF0000u);
            p = fmaf(ql, kl, p);
            p = fmaf(qh, kh, p);
        }
        p += __shfl_xor(p, 1);
        p += __shfl_xor(p, 2);
        float sc = p * 0.0625f;           // /sqrt(256)
        bool valid = (j0 + t) < m;
        if (valid) wmax = fmaxf(wmax, sc);
        if ((lane & 3) == 0 && valid) {
            int bb = lane >> 5;
            int h  = (lane >> 2) & 7;
            s[((size_t)bb * m + (j0 + t)) * NH + h] = sc;
        }
    }

    #pragma unroll
    for (int off = 1; off <= 32; off <<= 1)
        wmax = fmaxf(wmax, __shfl_xor(wmax, off));
    if (lane == 0) partials[wave] = wmax;
}

// K1b: reduce 80k wave-partials -> gmax. 128 blocks, 128 atomicMax total.
__global__ __launch_bounds__(256) void k_reduce_max(
    const float* __restrict__ partials, int nwaves, unsigned* __restrict__ gmax)
{
    float mx = -INFINITY;
    for (int i = blockIdx.x * blockDim.x + threadIdx.x; i < nwaves;
         i += gridDim.x * blockDim.x)
        mx = fmaxf(mx, partials[i]);
    #pragma unroll
    for (int off = 1; off <= 32; off <<= 1)
        mx = fmaxf(mx, __shfl_xor(mx, off));
    __shared__ float sm[4];
    if ((threadIdx.x & 63) == 0) sm[threadIdx.x >> 6] = mx;
    __syncthreads();
    if (threadIdx.x == 0) {
        float bm = fmaxf(fmaxf(sm[0], sm[1]), fmaxf(sm[2], sm[3]));
        if (bm > -INFINITY) atomicMax(gmax, f2ord(bm));
    }
}

// K2: ex = exp(s - M) in-place; atomicAdd into seg. ELEMENT-per-thread:
// consecutive lanes = consecutive heads of the same edge -> a wave's atomic
// instruction touches 8 clustered seg rows, not 64 random lines.
__global__ __launch_bounds__(256) void k_exp_seg(
    float* __restrict__ s, const int* __restrict__ r,
    const unsigned* __restrict__ gmax, float* __restrict__ seg, int m)
{
    float M = ord2f(*gmax);
    size_t total = (size_t)B * m * NH;
    for (size_t i = blockIdx.x * (size_t)blockDim.x + threadIdx.x; i < total;
         i += (size_t)gridDim.x * blockDim.x) {
        float ex = expf(s[i] - M);
        s[i] = ex;
        size_t bj = i >> 3;               // bb*m + j
        int h  = (int)(i & 7);
        int bb = (bj >= (size_t)m) ? 1 : 0;
        int j  = (int)(bj - (size_t)bb * m);
        atomicAdd(&seg[((size_t)r[j] * B + bb) * NH + h], ex);
    }
}

// K3: one thread per (bb, edge). out = ex / (seg + eps), float4 in-place.
__global__ __launch_bounds__(256) void k_norm(
    float* __restrict__ s, const int* __restrict__ r,
    const float* __restrict__ seg, int m)
{
    int i = blockIdx.x * blockDim.x + threadIdx.x;
    int total = B * m;
    if (i >= total) return;
    int bb = (i >= m) ? 1 : 0;
    int j  = i - bb * m;
    const float4* sg = (const float4*)(seg + ((size_t)r[j] * B + bb) * NH);
    float4* sp = (float4*)(s + (size_t)i * NH);
    float4 d0 = sg[0], d1 = sg[1];
    float4 x0 = sp[0], x1 = sp[1];
    x0.x /= (d0.x + 1e-16f); x0.y /= (d0.y + 1e-16f);
    x0.z /= (d0.z + 1e-16f); x0.w /= (d0.w + 1e-16f);
    x1.x /= (d1.x + 1e-16f); x1.y /= (d1.y + 1e-16f);
    x1.z /= (d1.z + 1e-16f); x1.w /= (d1.w + 1e-16f);
    sp[0] = x0; sp[1] = x1;
}

extern "C" void kernel_launch(void* const* d_in, const int* in_sizes, int n_in,
                              void* d_out, int out_size, void* d_ws, size_t ws_size,
                              hipStream_t stream) {
    const float* q = (const float*)d_in[0];
    const float* k = (const float*)d_in[1];
    const int*   e = (const int*)d_in[2];
    const int*   r = (const int*)d_in[3];
    float* s = (float*)d_out;

    int n = in_sizes[0] / (B * D);          // 20000
    int m = in_sizes[3];                    // 320000

    int nwaves = (m + EPW - 1) / EPW;       // 80000

    // ws layout: gmax @0 (16B) | seg | partials | qc | kc
    size_t seg_bytes  = (size_t)n * B * NH * sizeof(float);         // 1.28 MB
    size_t part_bytes = ((size_t)nwaves * sizeof(float) + 15) & ~15ull;
    size_t row_bytes  = (size_t)n * B * D * sizeof(unsigned short); // 20.48 MB
    unsigned* gmax     = (unsigned*)d_ws;
    float*    seg      = (float*)((char*)d_ws + 16);
    float*    partials = (float*)((char*)d_ws + 16 + seg_bytes);
    ushort*   qc       = (ushort*)((char*)d_ws + 16 + seg_bytes + part_bytes);
    ushort*   kc       = (ushort*)((char*)d_ws + 16 + seg_bytes + part_bytes + row_bytes);

    hipMemsetAsync(d_ws, 0, 16 + seg_bytes, stream);

    int sblocks = (nwaves + 3) / 4;
    int nblocks = (B * m + 255) / 256;

    k_conv<<<4096, 256, 0, stream>>>(q, k, (ushort4*)qc, (ushort4*)kc, n);
    k_scores_bf<<<sblocks, 256, 0, stream>>>(qc, kc, e, s, partials, m);
    k_reduce_max<<<128, 256, 0, stream>>>(partials, nwaves, gmax);
    k_exp_seg<<<4096, 256, 0, stream>>>(s, r, gmax, seg, m);
    k_norm<<<nblocks, 256, 0, stream>>>(s, r, seg, m);
}